// Round 9
// baseline (2931.183 us; speedup 1.0000x reference)
//
#include <hip/hip_runtime.h>

// Problem constants
#define NB 256   // batch
#define TT 256   // time steps
#define II 512   // input dim
#define HH 512   // hidden dim
#define GG 1536  // 3*H gates

typedef unsigned short ushort_t;
typedef unsigned int uint_t;
typedef unsigned long long ull_t;
typedef __attribute__((ext_vector_type(8))) short short8;   // 8 x bf16 (4 VGPRs)
typedef __attribute__((ext_vector_type(4))) float f32x4;    // MFMA accumulator

typedef __attribute__((address_space(3))) void lds_void;
typedef const __attribute__((address_space(1))) void glb_void;

__device__ __forceinline__ ushort_t f2bf(float f) {
  union { float f; unsigned int u; } x; x.f = f;
  unsigned int r = x.u + 0x7FFFu + ((x.u >> 16) & 1u);  // RNE
  return (ushort_t)(r >> 16);
}
__device__ __forceinline__ float bf2f(ushort_t b) {
  union { unsigned int u; float f; } x; x.u = ((unsigned int)b) << 16;
  return x.f;
}
__device__ __forceinline__ float sigmoidf_(float x) {
  return __fdividef(1.0f, 1.0f + __expf(-x));
}
__device__ __forceinline__ float tanhf_(float x) {
  float t = __expf(2.0f * x);
  return 1.0f - __fdividef(2.0f, t + 1.0f);
}
__device__ __forceinline__ short8 pack8(float4 a, float4 b) {
  short8 r;
  r[0] = (short)f2bf(a.x); r[1] = (short)f2bf(a.y);
  r[2] = (short)f2bf(a.z); r[3] = (short)f2bf(a.w);
  r[4] = (short)f2bf(b.x); r[5] = (short)f2bf(b.y);
  r[6] = (short)f2bf(b.z); r[7] = (short)f2bf(b.w);
  return r;
}

// ---------------------------------------------------------------------------
// is_init canonicalization -> uint8 mask (handles u8/i32/f32/i64 storage).
__global__ void mask_detect_kernel(const unsigned char* __restrict__ src,
                                   unsigned char* __restrict__ mask8) {
  __shared__ int fByte, fOdd;
  const int tid = threadIdx.x;
  if (tid == 0) { fByte = 0; fOdd = 0; }
  __syncthreads();
  const uint_t* w = (const uint_t*)src;
  int ab = 0, ao = 0;
  for (int i = tid; i < NB * TT; i += blockDim.x) {
    if ((i & 3) == 1 && src[i]) ab = 1;
    if (i < 16384 && (i & 1) == 1 && w[i]) ao = 1;
  }
  if (ab) fByte = 1;
  if (ao) fOdd = 1;
  __syncthreads();
  const int isByte = fByte, isW32 = fOdd;
  for (int i = tid; i < NB * TT; i += blockDim.x) {
    unsigned char m;
    if (isByte)      m = src[i] ? 1 : 0;
    else if (isW32)  m = w[i] ? 1 : 0;
    else             m = w[2 * i] ? 1 : 0;
    mask8[i] = m;
  }
}

// ---------------------------------------------------------------------------
__global__ void cvt_f2bf(const float* __restrict__ src, ushort_t* __restrict__ dst,
                         int n4) {
  int stride = gridDim.x * blockDim.x;
  for (int i = blockIdx.x * blockDim.x + threadIdx.x; i < n4; i += stride) {
    const float4 v = reinterpret_cast<const float4*>(src)[i];
    ushort4 o;
    o.x = f2bf(v.x); o.y = f2bf(v.y); o.z = f2bf(v.z); o.w = f2bf(v.w);
    reinterpret_cast<ushort4*>(dst)[i] = o;
  }
}

// ---------------------------------------------------------------------------
// Pack W_hh [1536][512] f32 into MFMA-B-fragment order (bf16):
// Wpk[((tile*16+kk)*64 + lane)*8 + e] = W[tile*16 + (lane&15)][kk*32 + (lane>>4)*8 + e]
__global__ void pack_whh(const float* __restrict__ W, ushort_t* __restrict__ out) {
  int idx = blockIdx.x * blockDim.x + threadIdx.x;  // 96*16*64 = 98304
  if (idx >= 96 * 16 * 64) return;
  int l = idx & 63;
  int tk = idx >> 6;
  int tile = tk >> 4, kk = tk & 15;
  int row = tile * 16 + (l & 15);
  int k = kk * 32 + (l >> 4) * 8;
  const float* s = W + (size_t)row * HH + k;
  short8 v;
#pragma unroll
  for (int e = 0; e < 8; ++e) v[e] = (short)f2bf(s[e]);
  *reinterpret_cast<short8*>(out + (size_t)idx * 8) = v;
}

// ---------------------------------------------------------------------------
// GEMM: C[m][c] = sum_k A[m][k]*B[c][k] + bias[c].  (unchanged)
template <int AF32, int CF32>
__global__ __launch_bounds__(256) void gemm_bt(
    const void* __restrict__ Av, const ushort_t* __restrict__ B,
    const float* __restrict__ bias, void* __restrict__ Cv, int NC) {
  __shared__ ushort_t As[128 * 32];
  __shared__ ushort_t Bs[128 * 32];
  const int tid = threadIdx.x;
  const int lane = tid & 63;
  const int w = tid >> 6;
  const int wr = w >> 1, wc = w & 1;
  const int c15 = lane & 15, l4 = lane >> 4;
  const int mbase = blockIdx.x * 128;
  const int nbase = blockIdx.y * 128;

  const int rs = tid >> 2;
  const int kb = (tid & 3) * 8;

  f32x4 acc[4][4] = {};

  const float4* Bg = reinterpret_cast<const float4*>(B);
  auto bIdx = [&](int c, int kt) {
    return ((size_t)(nbase + rs + 64 * c) * 512 + kt * 32 + kb) >> 3;
  };
  float4 rb0 = Bg[bIdx(0, 0)], rb1 = Bg[bIdx(1, 0)];

  const float4* Agf = reinterpret_cast<const float4*>(Av);
  auto aEl = [&](int c, int kt) {
    return (size_t)(mbase + rs + 64 * c) * 512 + kt * 32 + kb;
  };
  float4 a0a, a0b, a1a, a1b;
  float4 h0, h1;
  if constexpr (AF32) {
    a0a = Agf[aEl(0, 0) >> 2]; a0b = Agf[(aEl(0, 0) >> 2) + 1];
    a1a = Agf[aEl(1, 0) >> 2]; a1b = Agf[(aEl(1, 0) >> 2) + 1];
  } else {
    h0 = Agf[aEl(0, 0) >> 3];
    h1 = Agf[aEl(1, 0) >> 3];
  }

  for (int kt = 0; kt < 16; ++kt) {
    __syncthreads();
    if constexpr (AF32) {
      *reinterpret_cast<short8*>(&As[(size_t)tid * 8]) = pack8(a0a, a0b);
      *reinterpret_cast<short8*>(&As[(size_t)(tid + 256) * 8]) = pack8(a1a, a1b);
    } else {
      reinterpret_cast<float4*>(As)[tid] = h0;
      reinterpret_cast<float4*>(As)[tid + 256] = h1;
    }
    reinterpret_cast<float4*>(Bs)[tid] = rb0;
    reinterpret_cast<float4*>(Bs)[tid + 256] = rb1;
    if (kt < 15) {
      if constexpr (AF32) {
        a0a = Agf[aEl(0, kt + 1) >> 2]; a0b = Agf[(aEl(0, kt + 1) >> 2) + 1];
        a1a = Agf[aEl(1, kt + 1) >> 2]; a1b = Agf[(aEl(1, kt + 1) >> 2) + 1];
      } else {
        h0 = Agf[aEl(0, kt + 1) >> 3];
        h1 = Agf[aEl(1, kt + 1) >> 3];
      }
      rb0 = Bg[bIdx(0, kt + 1)]; rb1 = Bg[bIdx(1, kt + 1)];
    }
    __syncthreads();
    short8 af[4], bq[4];
#pragma unroll
    for (int m = 0; m < 4; ++m)
      af[m] = *reinterpret_cast<const short8*>(&As[(wr * 64 + m * 16 + c15) * 32 + l4 * 8]);
#pragma unroll
    for (int n = 0; n < 4; ++n)
      bq[n] = *reinterpret_cast<const short8*>(&Bs[(wc * 64 + n * 16 + c15) * 32 + l4 * 8]);
#pragma unroll
    for (int m = 0; m < 4; ++m)
#pragma unroll
      for (int n = 0; n < 4; ++n)
        acc[m][n] = __builtin_amdgcn_mfma_f32_16x16x32_bf16(af[m], bq[n], acc[m][n], 0, 0, 0);
  }

#pragma unroll
  for (int n = 0; n < 4; ++n) {
    const int col = nbase + wc * 64 + n * 16 + c15;
    const float bv = bias[col];
#pragma unroll
    for (int m = 0; m < 4; ++m) {
      const int row = mbase + wr * 64 + m * 16 + l4 * 4;
#pragma unroll
      for (int q = 0; q < 4; ++q) {
        const float v = acc[m][n][q] + bv;
        if constexpr (CF32)
          reinterpret_cast<float*>(Cv)[(size_t)(row + q) * NC + col] = v;
        else
          reinterpret_cast<ushort_t*>(Cv)[(size_t)(row + q) * NC + col] = f2bf(v);
      }
    }
  }
}

// ---------------------------------------------------------------------------
// GRU recurrence v7. 128 blocks x 256 threads. Block (a=bid&7, b=bid>>3).
// Changes vs v6 (8.1us/step, latency-bound):
//  - publish: LDS-staged, 16B coalesced PLAIN stores + RELEASE flag
//    (buffer_wbl2 writeback-only; W stays in L2). No per-element sc1 stores.
//  - hA stored in MFMA-fragment order w/ kk-XOR swizzle: af ds_read_b128 is
//    stride-16B consecutive = conflict-free (v6's swizzle was 8-way).
//  - W gates r,z parked in LDS once (128 KB DMA prologue); gate n streamed
//    from L2 (64 KB/step) -> 3x less L2 W traffic, no HBM W refetch.
// LDS map (ushort idx): Wlds 0..65535 | hAf 65536..73727 | xiL 73728..79871
//                       | hStage 79872..81023   (total 162048 B)
__global__ __launch_bounds__(256, 1) void gru_rec(
    const ushort_t* __restrict__ xi, const ushort_t* __restrict__ Wpk,
    const float* __restrict__ hx, const float* __restrict__ bhh,
    const unsigned char* __restrict__ mask8,
    ushort_t* __restrict__ hs, float* __restrict__ hT,
    char* __restrict__ xch, uint_t* __restrict__ flags) {
  extern __shared__ ushort_t smem[];
  const int HAF_U = 65536, XIL_U = 73728, HST_U = 79872;

  const int tid = threadIdx.x;
  const int lane = tid & 63;
  const int w = tid >> 6;              // wave 0..3 -> col-tile
  const int c15 = lane & 15, l4 = lane >> 4;
  const int bid = blockIdx.x;
  const int a = bid & 7;               // hidden-col group
  const int b = bid >> 3;              // sample group (cluster)
  const int n0 = b * 16;

  const int jl = w * 16 + c15;         // [0,64) local hidden col
  const int jfull = a * 64 + jl;       // [0,512)
  const float br = bhh[jfull], bz = bhh[512 + jfull], bn = bhh[1024 + jfull];

  // gate-n W fragment base (streamed from L2)
  const int wb2 = ((2 * 32 + a * 4 + w) * 16) * 512 + lane * 8;

  // ---- prologue DMA: W gates r,z -> LDS (32 x 1KB per wave)
#pragma unroll
  for (int g = 0; g < 2; ++g)
#pragma unroll
    for (int kk = 0; kk < 16; ++kk)
      __builtin_amdgcn_global_load_lds(
          (glb_void*)(Wpk + ((size_t)((g * 32 + a * 4 + w) * 16 + kk)) * 512 + lane * 8),
          (lds_void*)(smem + w * 16384 + (g * 16 + kk) * 512 + lane * 8), 16, 0, 0);

  // xi DMA geometry: 384 chunks = [16 s][3 g][8 p]; thread: c=tid, c=tid+256
  size_t xg0, xg1 = 0;
  {
    int c = tid, s = c / 24, r = c % 24, g = r >> 3, p = r & 7;
    xg0 = ((size_t)(n0 + s) * TT) * GG + g * 512 + a * 64 + p * 8;
    if (tid < 128) {
      c = tid + 256; s = c / 24; r = c % 24; g = r >> 3; p = r & 7;
      xg1 = ((size_t)(n0 + s) * TT) * GG + g * 512 + a * 64 + p * 8;
    }
  }
  const int xl0 = tid * 8, xl1 = (tid + 256) * 8;

  // exchange slots for this cluster
  char* slot0 = xch + (size_t)(b * 2) * 16384;
  char* slot1 = xch + (size_t)(b * 2 + 1) * 16384;

  // ---- prologue: h(0) = mask0 ? 0 : hx[:,0,:]; publish (plain) to slot0
  float h[4];
#pragma unroll
  for (int q = 0; q < 4; ++q) {
    const int s = l4 * 4 + q;
    const bool mk0 = mask8[(size_t)(n0 + s) * TT] != 0;
    const float v = mk0 ? 0.0f : hx[((size_t)(n0 + s) * TT) * HH + jfull];
    h[q] = v;
    *(ushort_t*)(slot0 + s * 1024 + jfull * 2) = f2bf(v);
  }
  __syncthreads();   // all publish stores complete in L2
  if (tid == 0)
    __hip_atomic_store(&flags[bid * 32], 1u, __ATOMIC_RELEASE,
                       __HIP_MEMORY_SCOPE_AGENT);  // wbl2 writeback + sc1 flag

  for (int t = 0; t < TT; ++t) {
    // ---- issue xi(t) DMA into buffer t&1 (overlaps the spin)
    ushort_t* xb = smem + XIL_U + (t & 1) * 3072;
    __builtin_amdgcn_global_load_lds((glb_void*)(xi + xg0 + (size_t)t * GG),
                                     (lds_void*)(xb + xl0), 16, 0, 0);
    if (tid < 128)
      __builtin_amdgcn_global_load_lds((glb_void*)(xi + xg1 + (size_t)t * GG),
                                       (lds_void*)(xb + xl1), 16, 0, 0);

    // ---- spin until cluster peers published h(t)
    if (tid < 8) {
      const uint_t tgt = (uint_t)(t + 1);
      while (__hip_atomic_load(&flags[(b * 8 + tid) * 32], __ATOMIC_RELAXED,
                               __HIP_MEMORY_SCOPE_AGENT) < tgt) {}
    }
    __syncthreads();   // B1

    // ---- gather h(t) 16KB from L3 (sc1, lane-consecutive 8B = coalesced)
    // -> hAf in MFMA-fragment order with kk-XOR swizzle
    const char* src = (t & 1) ? slot1 : slot0;
#pragma unroll
    for (int i = 0; i < 8; ++i) {
      const int c = tid + i * 256;           // 8B chunk id [0,2048)
      const int s = c >> 7, c7 = c & 127;
      const int kk = c7 >> 3, sub = (c >> 1) & 3, e2 = (c & 1) * 8;
      const ull_t v = __hip_atomic_load((const ull_t*)(src + s * 1024 + c7 * 8),
                                        __ATOMIC_RELAXED,
                                        __HIP_MEMORY_SCOPE_AGENT);
      *(ull_t*)((char*)smem + HAF_U * 2 + kk * 1024 +
                ((sub * 256 + s * 16 + e2) ^ ((kk & 7) << 4))) = v;
    }

    // next-step mask bytes
    const bool domask = (t + 1 < TT);
    const int tn = domask ? (t + 1) : t;
    unsigned char mkv[4];
#pragma unroll
    for (int q = 0; q < 4; ++q)
      mkv[q] = mask8[(size_t)(n0 + l4 * 4 + q) * TT + tn];

    __syncthreads();   // B2: hAf ready; xi + W DMA drained

    // ---- MFMA: af conflict-free b128; W r,z from LDS; W n from L2
    short8 af[16];
#pragma unroll
    for (int kk = 0; kk < 16; ++kk)
      af[kk] = *(const short8*)((char*)smem + HAF_U * 2 + kk * 1024 +
                                ((lane * 16) ^ ((kk & 7) << 4)));

    f32x4 a0 = {0.f, 0.f, 0.f, 0.f}, a1 = a0, a2 = a0;
#pragma unroll
    for (int kk = 0; kk < 16; ++kk) {
      const short8 w0 = *(const short8*)(smem + w * 16384 + kk * 512 + lane * 8);
      const short8 w1 = *(const short8*)(smem + w * 16384 + (16 + kk) * 512 + lane * 8);
      const short8 w2 = *(const short8*)(Wpk + wb2 + kk * 512);
      a0 = __builtin_amdgcn_mfma_f32_16x16x32_bf16(af[kk], w0, a0, 0, 0, 0);
      a1 = __builtin_amdgcn_mfma_f32_16x16x32_bf16(af[kk], w1, a1, 0, 0, 0);
      a2 = __builtin_amdgcn_mfma_f32_16x16x32_bf16(af[kk], w2, a2, 0, 0, 0);
    }

    // ---- gates + h update; hs nontemporal; stage h(t+1) in LDS
#pragma unroll
    for (int q = 0; q < 4; ++q) {
      const int s = l4 * 4 + q;
      const float xr = bf2f(xb[s * 192 + jl]);
      const float xz = bf2f(xb[s * 192 + 64 + jl]);
      const float xn = bf2f(xb[s * 192 + 128 + jl]);
      const float rr = sigmoidf_(xr + a0[q] + br);
      const float zz = sigmoidf_(xz + a1[q] + bz);
      const float nn = tanhf_(xn + rr * (a2[q] + bn));
      const float hnew = (1.0f - zz) * nn + zz * h[q];
      __builtin_nontemporal_store(
          f2bf(hnew), &hs[((size_t)(n0 + s) * TT + t) * HH + jfull]);
      const float hp = (domask && mkv[q]) ? 0.0f : hnew;
      h[q] = hp;
      smem[HST_U + s * 72 + jl] = f2bf(hp);
    }
    __syncthreads();   // B3: hStage ready; hAf reads done

    if (domask) {
      // ---- publish: 128 threads x 16B coalesced plain stores
      char* dst = ((t + 1) & 1) ? slot1 : slot0;
      if (tid < 128) {
        const int s = tid >> 3, o = tid & 7;
        *(float4*)(dst + s * 1024 + a * 128 + o * 16) =
            *(const float4*)(smem + HST_U + s * 72 + o * 8);
      }
      __syncthreads();  // B4: publish stores complete in L2
      if (tid == 0)
        __hip_atomic_store(&flags[bid * 32], (uint_t)(t + 2), __ATOMIC_RELEASE,
                           __HIP_MEMORY_SCOPE_AGENT);
    }
  }

  // ---- epilogue: final h (unmasked) -> hT f32
#pragma unroll
  for (int q = 0; q < 4; ++q)
    hT[(size_t)(n0 + l4 * 4 + q) * HH + jfull] = h[q];
}

// ---------------------------------------------------------------------------
// hx_out[n,t,:] = hT[n,:]  (f32, overwrites the hs scratch region after gemm3)
__global__ void bcast_hT(const float* __restrict__ hT, float* __restrict__ dst) {
  const float4* s = (const float4*)hT;
  float4* d = (float4*)dst;
  const int total = NB * TT * HH / 4;
  const int stride = gridDim.x * blockDim.x;
  for (int c = blockIdx.x * blockDim.x + threadIdx.x; c < total; c += stride) {
    int n = c >> 15;
    int j4 = c & 127;
    d[c] = s[(n << 7) | j4];
  }
}

// ---------------------------------------------------------------------------
extern "C" void kernel_launch(void* const* d_in, const int* in_sizes, int n_in,
                              void* d_out, int out_size, void* d_ws, size_t ws_size,
                              hipStream_t stream) {
  const float* x    = (const float*)d_in[0];
  const float* hx   = (const float*)d_in[1];
  const float* Wih  = (const float*)d_in[2];
  const float* Whh  = (const float*)d_in[3];
  const float* bih  = (const float*)d_in[4];
  const float* bhh  = (const float*)d_in[5];
  const float* Wout = (const float*)d_in[6];
  const float* bout = (const float*)d_in[7];
  const unsigned char* isinit = (const unsigned char*)d_in[8];

  char* ws = (char*)d_ws;
  ushort_t* xi    = (ushort_t*)(ws);
  ushort_t* wihb  = (ushort_t*)(ws + 201326592);
  ushort_t* whhp  = (ushort_t*)(ws + 202899456);
  ushort_t* woutb = (ushort_t*)(ws + 204472320);
  unsigned char* mask8 = (unsigned char*)(ws + 204996608);
  float*    hTbuf = (float*)(ws + 205062144);
  uint_t*   flags = (uint_t*)(ws + 205586432);
  char*     xch   = (char*)(ws + 205602816);

  float* out1 = (float*)d_out;                       // output [N,T,H] f32
  float* out2 = out1 + (size_t)NB * TT * HH;         // hx_out [N,T,H] f32
  ushort_t* hsb = (ushort_t*)out2;  // hs bf16 scratch until bcast overwrites

  hipMemsetAsync(flags, 0, 128 * 32 * sizeof(uint_t), stream);
  mask_detect_kernel<<<1, 1024, 0, stream>>>(isinit, mask8);
  cvt_f2bf<<<768, 256, 0, stream>>>(Wih, wihb, GG * II / 4);
  cvt_f2bf<<<256, 256, 0, stream>>>(Wout, woutb, HH * HH / 4);
  pack_whh<<<384, 256, 0, stream>>>(Whh, whhp);

  dim3 g1(512, 12);  // M/128 x 3H/128
  gemm_bt<1, 0><<<g1, 256, 0, stream>>>((const void*)x, wihb, bih, (void*)xi, GG);

  gru_rec<<<128, 256, 162048, stream>>>(xi, whhp, hx, bhh, mask8, hsb, hTbuf,
                                        xch, flags);

  dim3 g3(512, 4);   // M/128 x H/128
  gemm_bt<0, 1><<<g3, 256, 0, stream>>>((const void*)hsb, woutb, bout, (void*)out1, HH);

  bcast_hT<<<2048, 256, 0, stream>>>(hTbuf, out2);
}

// Round 10
// 1684.032 us; speedup vs baseline: 1.7406x; 1.7406x over previous
//
#include <hip/hip_runtime.h>

// Problem constants
#define NB 256   // batch
#define TT 256   // time steps
#define II 512   // input dim
#define HH 512   // hidden dim
#define GG 1536  // 3*H gates

typedef unsigned short ushort_t;
typedef unsigned int uint_t;
typedef unsigned long long ull_t;
typedef __attribute__((ext_vector_type(8))) short short8;   // 8 x bf16 (4 VGPRs)
typedef __attribute__((ext_vector_type(4))) float f32x4;    // MFMA accumulator

typedef __attribute__((address_space(3))) void lds_void;
typedef const __attribute__((address_space(1))) void glb_void;

__device__ __forceinline__ ushort_t f2bf(float f) {
  union { float f; unsigned int u; } x; x.f = f;
  unsigned int r = x.u + 0x7FFFu + ((x.u >> 16) & 1u);  // RNE
  return (ushort_t)(r >> 16);
}
__device__ __forceinline__ float bf2f(ushort_t b) {
  union { unsigned int u; float f; } x; x.u = ((unsigned int)b) << 16;
  return x.f;
}
__device__ __forceinline__ float sigmoidf_(float x) {
  return __fdividef(1.0f, 1.0f + __expf(-x));
}
__device__ __forceinline__ float tanhf_(float x) {
  float t = __expf(2.0f * x);
  return 1.0f - __fdividef(2.0f, t + 1.0f);
}
__device__ __forceinline__ short8 pack8(float4 a, float4 b) {
  short8 r;
  r[0] = (short)f2bf(a.x); r[1] = (short)f2bf(a.y);
  r[2] = (short)f2bf(a.z); r[3] = (short)f2bf(a.w);
  r[4] = (short)f2bf(b.x); r[5] = (short)f2bf(b.y);
  r[6] = (short)f2bf(b.z); r[7] = (short)f2bf(b.w);
  return r;
}

// ---------------------------------------------------------------------------
// is_init canonicalization -> uint8 mask (handles u8/i32/f32/i64 storage).
__global__ void mask_detect_kernel(const unsigned char* __restrict__ src,
                                   unsigned char* __restrict__ mask8) {
  __shared__ int fByte, fOdd;
  const int tid = threadIdx.x;
  if (tid == 0) { fByte = 0; fOdd = 0; }
  __syncthreads();
  const uint_t* w = (const uint_t*)src;
  int ab = 0, ao = 0;
  for (int i = tid; i < NB * TT; i += blockDim.x) {
    if ((i & 3) == 1 && src[i]) ab = 1;
    if (i < 16384 && (i & 1) == 1 && w[i]) ao = 1;
  }
  if (ab) fByte = 1;
  if (ao) fOdd = 1;
  __syncthreads();
  const int isByte = fByte, isW32 = fOdd;
  for (int i = tid; i < NB * TT; i += blockDim.x) {
    unsigned char m;
    if (isByte)      m = src[i] ? 1 : 0;
    else if (isW32)  m = w[i] ? 1 : 0;
    else             m = w[2 * i] ? 1 : 0;
    mask8[i] = m;
  }
}

// ---------------------------------------------------------------------------
__global__ void cvt_f2bf(const float* __restrict__ src, ushort_t* __restrict__ dst,
                         int n4) {
  int stride = gridDim.x * blockDim.x;
  for (int i = blockIdx.x * blockDim.x + threadIdx.x; i < n4; i += stride) {
    const float4 v = reinterpret_cast<const float4*>(src)[i];
    ushort4 o;
    o.x = f2bf(v.x); o.y = f2bf(v.y); o.z = f2bf(v.z); o.w = f2bf(v.w);
    reinterpret_cast<ushort4*>(dst)[i] = o;
  }
}

// ---------------------------------------------------------------------------
// Pack W_hh [1536][512] f32 into MFMA-B-fragment order (bf16):
// Wpk[((tile*16+kk)*64 + lane)*8 + e] = W[tile*16 + (lane&15)][kk*32 + (lane>>4)*8 + e]
__global__ void pack_whh(const float* __restrict__ W, ushort_t* __restrict__ out) {
  int idx = blockIdx.x * blockDim.x + threadIdx.x;  // 96*16*64 = 98304
  if (idx >= 96 * 16 * 64) return;
  int l = idx & 63;
  int tk = idx >> 6;
  int tile = tk >> 4, kk = tk & 15;
  int row = tile * 16 + (l & 15);
  int k = kk * 32 + (l >> 4) * 8;
  const float* s = W + (size_t)row * HH + k;
  short8 v;
#pragma unroll
  for (int e = 0; e < 8; ++e) v[e] = (short)f2bf(s[e]);
  *reinterpret_cast<short8*>(out + (size_t)idx * 8) = v;
}

// ---------------------------------------------------------------------------
// GEMM: C[m][c] = sum_k A[m][k]*B[c][k] + bias[c].  (unchanged)
template <int AF32, int CF32>
__global__ __launch_bounds__(256) void gemm_bt(
    const void* __restrict__ Av, const ushort_t* __restrict__ B,
    const float* __restrict__ bias, void* __restrict__ Cv, int NC) {
  __shared__ ushort_t As[128 * 32];
  __shared__ ushort_t Bs[128 * 32];
  const int tid = threadIdx.x;
  const int lane = tid & 63;
  const int w = tid >> 6;
  const int wr = w >> 1, wc = w & 1;
  const int c15 = lane & 15, l4 = lane >> 4;
  const int mbase = blockIdx.x * 128;
  const int nbase = blockIdx.y * 128;

  const int rs = tid >> 2;
  const int kb = (tid & 3) * 8;

  f32x4 acc[4][4] = {};

  const float4* Bg = reinterpret_cast<const float4*>(B);
  auto bIdx = [&](int c, int kt) {
    return ((size_t)(nbase + rs + 64 * c) * 512 + kt * 32 + kb) >> 3;
  };
  float4 rb0 = Bg[bIdx(0, 0)], rb1 = Bg[bIdx(1, 0)];

  const float4* Agf = reinterpret_cast<const float4*>(Av);
  auto aEl = [&](int c, int kt) {
    return (size_t)(mbase + rs + 64 * c) * 512 + kt * 32 + kb;
  };
  float4 a0a, a0b, a1a, a1b;
  float4 h0, h1;
  if constexpr (AF32) {
    a0a = Agf[aEl(0, 0) >> 2]; a0b = Agf[(aEl(0, 0) >> 2) + 1];
    a1a = Agf[aEl(1, 0) >> 2]; a1b = Agf[(aEl(1, 0) >> 2) + 1];
  } else {
    h0 = Agf[aEl(0, 0) >> 3];
    h1 = Agf[aEl(1, 0) >> 3];
  }

  for (int kt = 0; kt < 16; ++kt) {
    __syncthreads();
    if constexpr (AF32) {
      *reinterpret_cast<short8*>(&As[(size_t)tid * 8]) = pack8(a0a, a0b);
      *reinterpret_cast<short8*>(&As[(size_t)(tid + 256) * 8]) = pack8(a1a, a1b);
    } else {
      reinterpret_cast<float4*>(As)[tid] = h0;
      reinterpret_cast<float4*>(As)[tid + 256] = h1;
    }
    reinterpret_cast<float4*>(Bs)[tid] = rb0;
    reinterpret_cast<float4*>(Bs)[tid + 256] = rb1;
    if (kt < 15) {
      if constexpr (AF32) {
        a0a = Agf[aEl(0, kt + 1) >> 2]; a0b = Agf[(aEl(0, kt + 1) >> 2) + 1];
        a1a = Agf[aEl(1, kt + 1) >> 2]; a1b = Agf[(aEl(1, kt + 1) >> 2) + 1];
      } else {
        h0 = Agf[aEl(0, kt + 1) >> 3];
        h1 = Agf[aEl(1, kt + 1) >> 3];
      }
      rb0 = Bg[bIdx(0, kt + 1)]; rb1 = Bg[bIdx(1, kt + 1)];
    }
    __syncthreads();
    short8 af[4], bq[4];
#pragma unroll
    for (int m = 0; m < 4; ++m)
      af[m] = *reinterpret_cast<const short8*>(&As[(wr * 64 + m * 16 + c15) * 32 + l4 * 8]);
#pragma unroll
    for (int n = 0; n < 4; ++n)
      bq[n] = *reinterpret_cast<const short8*>(&Bs[(wc * 64 + n * 16 + c15) * 32 + l4 * 8]);
#pragma unroll
    for (int m = 0; m < 4; ++m)
#pragma unroll
      for (int n = 0; n < 4; ++n)
        acc[m][n] = __builtin_amdgcn_mfma_f32_16x16x32_bf16(af[m], bq[n], acc[m][n], 0, 0, 0);
  }

#pragma unroll
  for (int n = 0; n < 4; ++n) {
    const int col = nbase + wc * 64 + n * 16 + c15;
    const float bv = bias[col];
#pragma unroll
    for (int m = 0; m < 4; ++m) {
      const int row = mbase + wr * 64 + m * 16 + l4 * 4;
#pragma unroll
      for (int q = 0; q < 4; ++q) {
        const float v = acc[m][n][q] + bv;
        if constexpr (CF32)
          reinterpret_cast<float*>(Cv)[(size_t)(row + q) * NC + col] = v;
        else
          reinterpret_cast<ushort_t*>(Cv)[(size_t)(row + q) * NC + col] = f2bf(v);
      }
    }
  }
}

// ---------------------------------------------------------------------------
// GRU recurrence v8. Same structure as v7 (LDS W park, fragment-order hA,
// coalesced L3 gather) with the exchange protocol fixed:
//  - publish: LDS-staged then 256 x 8B sc1 RELAXED atomic stores
//    (write-through to L3; no dirty L2 lines from the exchange)
//  - flags: RELAXED (no buffer_wbl2 on the per-step critical path).
//    Ordering: __syncthreads drains vmcnt(0) => publishes ACKED at L3
//    before the flag store issues; consumers poll+gather via sc1 from L3.
// LDS map (ushort idx): Wlds 0..65535 | hAf 65536..73727 | xiL 73728..79871
//                       | hStage 79872..81023   (total 162048 B)
__global__ __launch_bounds__(256, 1) void gru_rec(
    const ushort_t* __restrict__ xi, const ushort_t* __restrict__ Wpk,
    const float* __restrict__ hx, const float* __restrict__ bhh,
    const unsigned char* __restrict__ mask8,
    ushort_t* __restrict__ hs, float* __restrict__ hT,
    char* __restrict__ xch, uint_t* __restrict__ flags) {
  extern __shared__ ushort_t smem[];
  const int HAF_U = 65536, XIL_U = 73728, HST_U = 79872;

  const int tid = threadIdx.x;
  const int lane = tid & 63;
  const int w = tid >> 6;              // wave 0..3 -> col-tile
  const int c15 = lane & 15, l4 = lane >> 4;
  const int bid = blockIdx.x;
  const int a = bid & 7;               // hidden-col group
  const int b = bid >> 3;              // sample group (cluster)
  const int n0 = b * 16;

  const int jl = w * 16 + c15;         // [0,64) local hidden col
  const int jfull = a * 64 + jl;       // [0,512)
  const float br = bhh[jfull], bz = bhh[512 + jfull], bn = bhh[1024 + jfull];

  // gate-n W fragment base (streamed from L2)
  const int wb2 = ((2 * 32 + a * 4 + w) * 16) * 512 + lane * 8;

  // ---- prologue DMA: W gates r,z -> LDS (32 x 1KB per wave)
#pragma unroll
  for (int g = 0; g < 2; ++g)
#pragma unroll
    for (int kk = 0; kk < 16; ++kk)
      __builtin_amdgcn_global_load_lds(
          (glb_void*)(Wpk + ((size_t)((g * 32 + a * 4 + w) * 16 + kk)) * 512 + lane * 8),
          (lds_void*)(smem + w * 16384 + (g * 16 + kk) * 512 + lane * 8), 16, 0, 0);

  // xi DMA geometry: 384 chunks = [16 s][3 g][8 p]; thread: c=tid, c=tid+256
  size_t xg0, xg1 = 0;
  {
    int c = tid, s = c / 24, r = c % 24, g = r >> 3, p = r & 7;
    xg0 = ((size_t)(n0 + s) * TT) * GG + g * 512 + a * 64 + p * 8;
    if (tid < 128) {
      c = tid + 256; s = c / 24; r = c % 24; g = r >> 3; p = r & 7;
      xg1 = ((size_t)(n0 + s) * TT) * GG + g * 512 + a * 64 + p * 8;
    }
  }
  const int xl0 = tid * 8, xl1 = (tid + 256) * 8;

  // exchange slots for this cluster
  char* slot0 = xch + (size_t)(b * 2) * 16384;
  char* slot1 = xch + (size_t)(b * 2 + 1) * 16384;

  // publish chunk for this thread: 8B of the block's 2KB slice
  const int ps = tid >> 4, po = tid & 15;

  // ---- prologue: h(0) = mask0 ? 0 : hx[:,0,:]; stage; publish sc1; flag
  float h[4];
#pragma unroll
  for (int q = 0; q < 4; ++q) {
    const int s = l4 * 4 + q;
    const bool mk0 = mask8[(size_t)(n0 + s) * TT] != 0;
    const float v = mk0 ? 0.0f : hx[((size_t)(n0 + s) * TT) * HH + jfull];
    h[q] = v;
    smem[HST_U + s * 72 + jl] = f2bf(v);
  }
  __syncthreads();
  {
    const ull_t v = *(const ull_t*)(smem + HST_U + ps * 72 + po * 4);
    __hip_atomic_store((ull_t*)(slot0 + ps * 1024 + a * 128 + po * 8), v,
                       __ATOMIC_RELAXED, __HIP_MEMORY_SCOPE_AGENT);
  }
  __syncthreads();   // vmcnt(0): publishes acked at L3
  if (tid == 0)
    __hip_atomic_store(&flags[bid * 32], 1u, __ATOMIC_RELAXED,
                       __HIP_MEMORY_SCOPE_AGENT);

  for (int t = 0; t < TT; ++t) {
    // ---- issue xi(t) DMA into buffer t&1 (overlaps the spin)
    ushort_t* xb = smem + XIL_U + (t & 1) * 3072;
    __builtin_amdgcn_global_load_lds((glb_void*)(xi + xg0 + (size_t)t * GG),
                                     (lds_void*)(xb + xl0), 16, 0, 0);
    if (tid < 128)
      __builtin_amdgcn_global_load_lds((glb_void*)(xi + xg1 + (size_t)t * GG),
                                       (lds_void*)(xb + xl1), 16, 0, 0);

    // ---- spin until cluster peers published h(t)
    if (tid < 8) {
      const uint_t tgt = (uint_t)(t + 1);
      while (__hip_atomic_load(&flags[(b * 8 + tid) * 32], __ATOMIC_RELAXED,
                               __HIP_MEMORY_SCOPE_AGENT) < tgt) {}
    }
    __syncthreads();   // B1

    // ---- gather h(t) 16KB from L3 (sc1, lane-consecutive 8B = coalesced)
    // -> hAf in MFMA-fragment order with kk-XOR swizzle
    const char* src = (t & 1) ? slot1 : slot0;
#pragma unroll
    for (int i = 0; i < 8; ++i) {
      const int c = tid + i * 256;           // 8B chunk id [0,2048)
      const int s = c >> 7, c7 = c & 127;
      const int kk = c7 >> 3, sub = (c >> 1) & 3, e2 = (c & 1) * 8;
      const ull_t v = __hip_atomic_load((const ull_t*)(src + s * 1024 + c7 * 8),
                                        __ATOMIC_RELAXED,
                                        __HIP_MEMORY_SCOPE_AGENT);
      *(ull_t*)((char*)smem + HAF_U * 2 + kk * 1024 +
                ((sub * 256 + s * 16 + e2) ^ ((kk & 7) << 4))) = v;
    }

    // next-step mask bytes
    const bool domask = (t + 1 < TT);
    const int tn = domask ? (t + 1) : t;
    unsigned char mkv[4];
#pragma unroll
    for (int q = 0; q < 4; ++q)
      mkv[q] = mask8[(size_t)(n0 + l4 * 4 + q) * TT + tn];

    __syncthreads();   // B2: hAf ready; xi + W DMA drained

    // ---- MFMA: af conflict-free b128; W r,z from LDS; W n from L2
    short8 af[16];
#pragma unroll
    for (int kk = 0; kk < 16; ++kk)
      af[kk] = *(const short8*)((char*)smem + HAF_U * 2 + kk * 1024 +
                                ((lane * 16) ^ ((kk & 7) << 4)));

    f32x4 a0 = {0.f, 0.f, 0.f, 0.f}, a1 = a0, a2 = a0;
#pragma unroll
    for (int kk = 0; kk < 16; ++kk) {
      const short8 w0 = *(const short8*)(smem + w * 16384 + kk * 512 + lane * 8);
      const short8 w1 = *(const short8*)(smem + w * 16384 + (16 + kk) * 512 + lane * 8);
      const short8 w2 = *(const short8*)(Wpk + wb2 + kk * 512);
      a0 = __builtin_amdgcn_mfma_f32_16x16x32_bf16(af[kk], w0, a0, 0, 0, 0);
      a1 = __builtin_amdgcn_mfma_f32_16x16x32_bf16(af[kk], w1, a1, 0, 0, 0);
      a2 = __builtin_amdgcn_mfma_f32_16x16x32_bf16(af[kk], w2, a2, 0, 0, 0);
    }

    // ---- gates + h update; hs nontemporal; stage h(t+1) in LDS
#pragma unroll
    for (int q = 0; q < 4; ++q) {
      const int s = l4 * 4 + q;
      const float xr = bf2f(xb[s * 192 + jl]);
      const float xz = bf2f(xb[s * 192 + 64 + jl]);
      const float xn = bf2f(xb[s * 192 + 128 + jl]);
      const float rr = sigmoidf_(xr + a0[q] + br);
      const float zz = sigmoidf_(xz + a1[q] + bz);
      const float nn = tanhf_(xn + rr * (a2[q] + bn));
      const float hnew = (1.0f - zz) * nn + zz * h[q];
      __builtin_nontemporal_store(
          f2bf(hnew), &hs[((size_t)(n0 + s) * TT + t) * HH + jfull]);
      const float hp = (domask && mkv[q]) ? 0.0f : hnew;
      h[q] = hp;
      smem[HST_U + s * 72 + jl] = f2bf(hp);
    }
    __syncthreads();   // B3: hStage ready; hAf reads done

    if (domask) {
      // ---- publish: 256 x 8B sc1 relaxed stores (write-through to L3)
      char* dst = ((t + 1) & 1) ? slot1 : slot0;
      const ull_t v = *(const ull_t*)(smem + HST_U + ps * 72 + po * 4);
      __hip_atomic_store((ull_t*)(dst + ps * 1024 + a * 128 + po * 8), v,
                         __ATOMIC_RELAXED, __HIP_MEMORY_SCOPE_AGENT);
      __syncthreads();  // B4: vmcnt(0) -> publishes acked at L3
      if (tid == 0)
        __hip_atomic_store(&flags[bid * 32], (uint_t)(t + 2), __ATOMIC_RELAXED,
                           __HIP_MEMORY_SCOPE_AGENT);
    }
  }

  // ---- epilogue: final h (unmasked) -> hT f32
#pragma unroll
  for (int q = 0; q < 4; ++q)
    hT[(size_t)(n0 + l4 * 4 + q) * HH + jfull] = h[q];
}

// ---------------------------------------------------------------------------
// hx_out[n,t,:] = hT[n,:]  (f32, overwrites the hs scratch region after gemm3)
__global__ void bcast_hT(const float* __restrict__ hT, float* __restrict__ dst) {
  const float4* s = (const float4*)hT;
  float4* d = (float4*)dst;
  const int total = NB * TT * HH / 4;
  const int stride = gridDim.x * blockDim.x;
  for (int c = blockIdx.x * blockDim.x + threadIdx.x; c < total; c += stride) {
    int n = c >> 15;
    int j4 = c & 127;
    d[c] = s[(n << 7) | j4];
  }
}

// ---------------------------------------------------------------------------
extern "C" void kernel_launch(void* const* d_in, const int* in_sizes, int n_in,
                              void* d_out, int out_size, void* d_ws, size_t ws_size,
                              hipStream_t stream) {
  const float* x    = (const float*)d_in[0];
  const float* hx   = (const float*)d_in[1];
  const float* Wih  = (const float*)d_in[2];
  const float* Whh  = (const float*)d_in[3];
  const float* bih  = (const float*)d_in[4];
  const float* bhh  = (const float*)d_in[5];
  const float* Wout = (const float*)d_in[6];
  const float* bout = (const float*)d_in[7];
  const unsigned char* isinit = (const unsigned char*)d_in[8];

  char* ws = (char*)d_ws;
  ushort_t* xi    = (ushort_t*)(ws);
  ushort_t* wihb  = (ushort_t*)(ws + 201326592);
  ushort_t* whhp  = (ushort_t*)(ws + 202899456);
  ushort_t* woutb = (ushort_t*)(ws + 204472320);
  unsigned char* mask8 = (unsigned char*)(ws + 204996608);
  float*    hTbuf = (float*)(ws + 205062144);
  uint_t*   flags = (uint_t*)(ws + 205586432);
  char*     xch   = (char*)(ws + 205602816);

  float* out1 = (float*)d_out;                       // output [N,T,H] f32
  float* out2 = out1 + (size_t)NB * TT * HH;         // hx_out [N,T,H] f32
  ushort_t* hsb = (ushort_t*)out2;  // hs bf16 scratch until bcast overwrites

  hipMemsetAsync(flags, 0, 128 * 32 * sizeof(uint_t), stream);
  mask_detect_kernel<<<1, 1024, 0, stream>>>(isinit, mask8);
  cvt_f2bf<<<768, 256, 0, stream>>>(Wih, wihb, GG * II / 4);
  cvt_f2bf<<<256, 256, 0, stream>>>(Wout, woutb, HH * HH / 4);
  pack_whh<<<384, 256, 0, stream>>>(Whh, whhp);

  dim3 g1(512, 12);  // M/128 x 3H/128
  gemm_bt<1, 0><<<g1, 256, 0, stream>>>((const void*)x, wihb, bih, (void*)xi, GG);

  gru_rec<<<128, 256, 162048, stream>>>(xi, whhp, hx, bhh, mask8, hsb, hTbuf,
                                        xch, flags);

  dim3 g3(512, 4);   // M/128 x H/128
  gemm_bt<0, 1><<<g3, 256, 0, stream>>>((const void*)hsb, woutb, bout, (void*)out1, HH);

  bcast_hT<<<2048, 256, 0, stream>>>(hTbuf, out2);
}

// Round 11
// 1669.308 us; speedup vs baseline: 1.7559x; 1.0088x over previous
//
#include <hip/hip_runtime.h>

// Problem constants
#define NB 256   // batch
#define TT 256   // time steps
#define II 512   // input dim
#define HH 512   // hidden dim
#define GG 1536  // 3*H gates

typedef unsigned short ushort_t;
typedef unsigned int uint_t;
typedef unsigned long long ull_t;
typedef __attribute__((ext_vector_type(8))) short short8;   // 8 x bf16 (4 VGPRs)
typedef __attribute__((ext_vector_type(4))) float f32x4;    // MFMA accumulator

typedef __attribute__((address_space(3))) void lds_void;
typedef const __attribute__((address_space(1))) void glb_void;

__device__ __forceinline__ ushort_t f2bf(float f) {
  union { float f; unsigned int u; } x; x.f = f;
  unsigned int r = x.u + 0x7FFFu + ((x.u >> 16) & 1u);  // RNE
  return (ushort_t)(r >> 16);
}
__device__ __forceinline__ float bf2f(ushort_t b) {
  union { unsigned int u; float f; } x; x.u = ((unsigned int)b) << 16;
  return x.f;
}
__device__ __forceinline__ float sigmoidf_(float x) {
  return __fdividef(1.0f, 1.0f + __expf(-x));
}
__device__ __forceinline__ float tanhf_(float x) {
  float t = __expf(2.0f * x);
  return 1.0f - __fdividef(2.0f, t + 1.0f);
}
__device__ __forceinline__ short8 pack8(float4 a, float4 b) {
  short8 r;
  r[0] = (short)f2bf(a.x); r[1] = (short)f2bf(a.y);
  r[2] = (short)f2bf(a.z); r[3] = (short)f2bf(a.w);
  r[4] = (short)f2bf(b.x); r[5] = (short)f2bf(b.y);
  r[6] = (short)f2bf(b.z); r[7] = (short)f2bf(b.w);
  return r;
}

// ---------------------------------------------------------------------------
// is_init canonicalization -> uint8 mask (handles u8/i32/f32/i64 storage).
__global__ void mask_detect_kernel(const unsigned char* __restrict__ src,
                                   unsigned char* __restrict__ mask8) {
  __shared__ int fByte, fOdd;
  const int tid = threadIdx.x;
  if (tid == 0) { fByte = 0; fOdd = 0; }
  __syncthreads();
  const uint_t* w = (const uint_t*)src;
  int ab = 0, ao = 0;
  for (int i = tid; i < NB * TT; i += blockDim.x) {
    if ((i & 3) == 1 && src[i]) ab = 1;
    if (i < 16384 && (i & 1) == 1 && w[i]) ao = 1;
  }
  if (ab) fByte = 1;
  if (ao) fOdd = 1;
  __syncthreads();
  const int isByte = fByte, isW32 = fOdd;
  for (int i = tid; i < NB * TT; i += blockDim.x) {
    unsigned char m;
    if (isByte)      m = src[i] ? 1 : 0;
    else if (isW32)  m = w[i] ? 1 : 0;
    else             m = w[2 * i] ? 1 : 0;
    mask8[i] = m;
  }
}

// ---------------------------------------------------------------------------
__global__ void cvt_f2bf(const float* __restrict__ src, ushort_t* __restrict__ dst,
                         int n4) {
  int stride = gridDim.x * blockDim.x;
  for (int i = blockIdx.x * blockDim.x + threadIdx.x; i < n4; i += stride) {
    const float4 v = reinterpret_cast<const float4*>(src)[i];
    ushort4 o;
    o.x = f2bf(v.x); o.y = f2bf(v.y); o.z = f2bf(v.z); o.w = f2bf(v.w);
    reinterpret_cast<ushort4*>(dst)[i] = o;
  }
}

// ---------------------------------------------------------------------------
// Pack W_hh [1536][512] f32 into MFMA-B-fragment order (bf16):
// Wpk[((tile*16+kk)*64 + lane)*8 + e] = W[tile*16 + (lane&15)][kk*32 + (lane>>4)*8 + e]
__global__ void pack_whh(const float* __restrict__ W, ushort_t* __restrict__ out) {
  int idx = blockIdx.x * blockDim.x + threadIdx.x;  // 96*16*64 = 98304
  if (idx >= 96 * 16 * 64) return;
  int l = idx & 63;
  int tk = idx >> 6;
  int tile = tk >> 4, kk = tk & 15;
  int row = tile * 16 + (l & 15);
  int k = kk * 32 + (l >> 4) * 8;
  const float* s = W + (size_t)row * HH + k;
  short8 v;
#pragma unroll
  for (int e = 0; e < 8; ++e) v[e] = (short)f2bf(s[e]);
  *reinterpret_cast<short8*>(out + (size_t)idx * 8) = v;
}

// ---------------------------------------------------------------------------
// GEMM: C[m][c] = sum_k A[m][k]*B[c][k] + bias[c].  (unchanged)
template <int AF32, int CF32>
__global__ __launch_bounds__(256) void gemm_bt(
    const void* __restrict__ Av, const ushort_t* __restrict__ B,
    const float* __restrict__ bias, void* __restrict__ Cv, int NC) {
  __shared__ ushort_t As[128 * 32];
  __shared__ ushort_t Bs[128 * 32];
  const int tid = threadIdx.x;
  const int lane = tid & 63;
  const int w = tid >> 6;
  const int wr = w >> 1, wc = w & 1;
  const int c15 = lane & 15, l4 = lane >> 4;
  const int mbase = blockIdx.x * 128;
  const int nbase = blockIdx.y * 128;

  const int rs = tid >> 2;
  const int kb = (tid & 3) * 8;

  f32x4 acc[4][4] = {};

  const float4* Bg = reinterpret_cast<const float4*>(B);
  auto bIdx = [&](int c, int kt) {
    return ((size_t)(nbase + rs + 64 * c) * 512 + kt * 32 + kb) >> 3;
  };
  float4 rb0 = Bg[bIdx(0, 0)], rb1 = Bg[bIdx(1, 0)];

  const float4* Agf = reinterpret_cast<const float4*>(Av);
  auto aEl = [&](int c, int kt) {
    return (size_t)(mbase + rs + 64 * c) * 512 + kt * 32 + kb;
  };
  float4 a0a, a0b, a1a, a1b;
  float4 h0, h1;
  if constexpr (AF32) {
    a0a = Agf[aEl(0, 0) >> 2]; a0b = Agf[(aEl(0, 0) >> 2) + 1];
    a1a = Agf[aEl(1, 0) >> 2]; a1b = Agf[(aEl(1, 0) >> 2) + 1];
  } else {
    h0 = Agf[aEl(0, 0) >> 3];
    h1 = Agf[aEl(1, 0) >> 3];
  }

  for (int kt = 0; kt < 16; ++kt) {
    __syncthreads();
    if constexpr (AF32) {
      *reinterpret_cast<short8*>(&As[(size_t)tid * 8]) = pack8(a0a, a0b);
      *reinterpret_cast<short8*>(&As[(size_t)(tid + 256) * 8]) = pack8(a1a, a1b);
    } else {
      reinterpret_cast<float4*>(As)[tid] = h0;
      reinterpret_cast<float4*>(As)[tid + 256] = h1;
    }
    reinterpret_cast<float4*>(Bs)[tid] = rb0;
    reinterpret_cast<float4*>(Bs)[tid + 256] = rb1;
    if (kt < 15) {
      if constexpr (AF32) {
        a0a = Agf[aEl(0, kt + 1) >> 2]; a0b = Agf[(aEl(0, kt + 1) >> 2) + 1];
        a1a = Agf[aEl(1, kt + 1) >> 2]; a1b = Agf[(aEl(1, kt + 1) >> 2) + 1];
      } else {
        h0 = Agf[aEl(0, kt + 1) >> 3];
        h1 = Agf[aEl(1, kt + 1) >> 3];
      }
      rb0 = Bg[bIdx(0, kt + 1)]; rb1 = Bg[bIdx(1, kt + 1)];
    }
    __syncthreads();
    short8 af[4], bq[4];
#pragma unroll
    for (int m = 0; m < 4; ++m)
      af[m] = *reinterpret_cast<const short8*>(&As[(wr * 64 + m * 16 + c15) * 32 + l4 * 8]);
#pragma unroll
    for (int n = 0; n < 4; ++n)
      bq[n] = *reinterpret_cast<const short8*>(&Bs[(wc * 64 + n * 16 + c15) * 32 + l4 * 8]);
#pragma unroll
    for (int m = 0; m < 4; ++m)
#pragma unroll
      for (int n = 0; n < 4; ++n)
        acc[m][n] = __builtin_amdgcn_mfma_f32_16x16x32_bf16(af[m], bq[n], acc[m][n], 0, 0, 0);
  }

#pragma unroll
  for (int n = 0; n < 4; ++n) {
    const int col = nbase + wc * 64 + n * 16 + c15;
    const float bv = bias[col];
#pragma unroll
    for (int m = 0; m < 4; ++m) {
      const int row = mbase + wr * 64 + m * 16 + l4 * 4;
#pragma unroll
      for (int q = 0; q < 4; ++q) {
        const float v = acc[m][n][q] + bv;
        if constexpr (CF32)
          reinterpret_cast<float*>(Cv)[(size_t)(row + q) * NC + col] = v;
        else
          reinterpret_cast<ushort_t*>(Cv)[(size_t)(row + q) * NC + col] = f2bf(v);
      }
    }
  }
}

// ---------------------------------------------------------------------------
// GRU recurrence v9. vs v8:
//  - gate-n W fragments hoisted into 16 short8 REGISTERS (loop-invariant; v8
//    re-loaded them from L2 serially every step with no TLP to hide latency)
//  - exchange slot is stored in MFMA-A-FRAGMENT order: publisher writes
//    fragment-ordered 8B sc1 stores; gather is linear lane-consecutive 8B
//    sc1 loads -> linear LDS writes -> linear conflict-free af b128 reads.
//    (kills v8's 16M bank conflicts on the gather-write side, no XOR at all)
// Fragment layout of slot: addr(s,j) = (j>>5)*1024 + (s + 16*((j&31)>>3))*16
//                                      + (j&7)*2
// LDS map (ushort idx): Wlds 0..65535 | hAf 65536..73727 | xiL 73728..79871
//                       | hStage 79872..81023   (total 162048 B)
__global__ __launch_bounds__(256, 1) void gru_rec(
    const ushort_t* __restrict__ xi, const ushort_t* __restrict__ Wpk,
    const float* __restrict__ hx, const float* __restrict__ bhh,
    const unsigned char* __restrict__ mask8,
    ushort_t* __restrict__ hs, float* __restrict__ hT,
    char* __restrict__ xch, uint_t* __restrict__ flags) {
  extern __shared__ ushort_t smem[];
  const int HAF_U = 65536, XIL_U = 73728, HST_U = 79872;

  const int tid = threadIdx.x;
  const int lane = tid & 63;
  const int w = tid >> 6;              // wave 0..3 -> col-tile
  const int c15 = lane & 15, l4 = lane >> 4;
  const int bid = blockIdx.x;
  const int a = bid & 7;               // hidden-col group
  const int b = bid >> 3;              // sample group (cluster)
  const int n0 = b * 16;

  const int jl = w * 16 + c15;         // [0,64) local hidden col
  const int jfull = a * 64 + jl;       // [0,512)
  const float br = bhh[jfull], bz = bhh[512 + jfull], bn = bhh[1024 + jfull];

  // ---- prologue DMA: W gates r,z -> LDS (32 x 1KB per wave)
#pragma unroll
  for (int g = 0; g < 2; ++g)
#pragma unroll
    for (int kk = 0; kk < 16; ++kk)
      __builtin_amdgcn_global_load_lds(
          (glb_void*)(Wpk + ((size_t)((g * 32 + a * 4 + w) * 16 + kk)) * 512 + lane * 8),
          (lds_void*)(smem + w * 16384 + (g * 16 + kk) * 512 + lane * 8), 16, 0, 0);

  // ---- gate-n W slice hoisted into registers (64 VGPRs, loaded ONCE)
  const int wb2 = ((2 * 32 + a * 4 + w) * 16) * 512 + lane * 8;
  short8 wn[16];
#pragma unroll
  for (int kk = 0; kk < 16; ++kk)
    wn[kk] = *(const short8*)(Wpk + wb2 + kk * 512);

  // xi DMA geometry: 384 chunks = [16 s][3 g][8 p]; thread: c=tid, c=tid+256
  size_t xg0, xg1 = 0;
  {
    int c = tid, s = c / 24, r = c % 24, g = r >> 3, p = r & 7;
    xg0 = ((size_t)(n0 + s) * TT) * GG + g * 512 + a * 64 + p * 8;
    if (tid < 128) {
      c = tid + 256; s = c / 24; r = c % 24; g = r >> 3; p = r & 7;
      xg1 = ((size_t)(n0 + s) * TT) * GG + g * 512 + a * 64 + p * 8;
    }
  }
  const int xl0 = tid * 8, xl1 = (tid + 256) * 8;

  // exchange slots for this cluster
  char* slot0 = xch + (size_t)(b * 2) * 16384;
  char* slot1 = xch + (size_t)(b * 2 + 1) * 16384;

  // publish geometry (fragment-order): thread -> (s, jq), 8B = 4 cols
  const int ps = tid >> 4, pj = tid & 15;
  const int pOff = (2 * a + (pj >> 3)) * 1024 +
                   (ps + 16 * ((pj >> 1) & 3)) * 16 + (pj & 1) * 8;
  const int pSrc = HST_U + ps * 72 + pj * 4;   // ushort idx into hStage

  // ---- prologue: h(0) = mask0 ? 0 : hx[:,0,:]; stage; publish sc1; flag
  float h[4];
#pragma unroll
  for (int q = 0; q < 4; ++q) {
    const int s = l4 * 4 + q;
    const bool mk0 = mask8[(size_t)(n0 + s) * TT] != 0;
    const float v = mk0 ? 0.0f : hx[((size_t)(n0 + s) * TT) * HH + jfull];
    h[q] = v;
    smem[HST_U + s * 72 + jl] = f2bf(v);
  }
  __syncthreads();
  {
    const ull_t v = *(const ull_t*)(smem + pSrc);
    __hip_atomic_store((ull_t*)(slot0 + pOff), v,
                       __ATOMIC_RELAXED, __HIP_MEMORY_SCOPE_AGENT);
  }
  __syncthreads();   // vmcnt(0): publishes acked at L3
  if (tid == 0)
    __hip_atomic_store(&flags[bid * 32], 1u, __ATOMIC_RELAXED,
                       __HIP_MEMORY_SCOPE_AGENT);

  for (int t = 0; t < TT; ++t) {
    // ---- issue xi(t) DMA into buffer t&1 (overlaps the spin)
    ushort_t* xb = smem + XIL_U + (t & 1) * 3072;
    __builtin_amdgcn_global_load_lds((glb_void*)(xi + xg0 + (size_t)t * GG),
                                     (lds_void*)(xb + xl0), 16, 0, 0);
    if (tid < 128)
      __builtin_amdgcn_global_load_lds((glb_void*)(xi + xg1 + (size_t)t * GG),
                                       (lds_void*)(xb + xl1), 16, 0, 0);

    // ---- spin until cluster peers published h(t)
    if (tid < 8) {
      const uint_t tgt = (uint_t)(t + 1);
      while (__hip_atomic_load(&flags[(b * 8 + tid) * 32], __ATOMIC_RELAXED,
                               __HIP_MEMORY_SCOPE_AGENT) < tgt) {}
    }
    __syncthreads();   // B1

    // ---- gather h(t): slot already fragment-ordered -> LINEAR copy to LDS
    const char* src = (t & 1) ? slot1 : slot0;
#pragma unroll
    for (int i = 0; i < 8; ++i) {
      const int c = tid + i * 256;           // 8B chunk id [0,2048)
      const ull_t v = __hip_atomic_load((const ull_t*)(src + c * 8),
                                        __ATOMIC_RELAXED,
                                        __HIP_MEMORY_SCOPE_AGENT);
      *(ull_t*)((char*)smem + HAF_U * 2 + c * 8) = v;
    }

    // next-step mask bytes
    const bool domask = (t + 1 < TT);
    const int tn = domask ? (t + 1) : t;
    unsigned char mkv[4];
#pragma unroll
    for (int q = 0; q < 4; ++q)
      mkv[q] = mask8[(size_t)(n0 + l4 * 4 + q) * TT + tn];

    __syncthreads();   // B2: hAf ready; xi + W DMA drained

    // ---- MFMA: af linear conflict-free b128; W r,z from LDS; W n from regs
    short8 af[16];
#pragma unroll
    for (int kk = 0; kk < 16; ++kk)
      af[kk] = *(const short8*)((char*)smem + HAF_U * 2 + kk * 1024 + lane * 16);

    f32x4 a0 = {0.f, 0.f, 0.f, 0.f}, a1 = a0, a2 = a0;
#pragma unroll
    for (int kk = 0; kk < 16; ++kk) {
      const short8 w0 = *(const short8*)(smem + w * 16384 + kk * 512 + lane * 8);
      const short8 w1 = *(const short8*)(smem + w * 16384 + (16 + kk) * 512 + lane * 8);
      a0 = __builtin_amdgcn_mfma_f32_16x16x32_bf16(af[kk], w0, a0, 0, 0, 0);
      a1 = __builtin_amdgcn_mfma_f32_16x16x32_bf16(af[kk], w1, a1, 0, 0, 0);
      a2 = __builtin_amdgcn_mfma_f32_16x16x32_bf16(af[kk], wn[kk], a2, 0, 0, 0);
    }

    // ---- gates + h update; hs nontemporal; stage h(t+1) in LDS
#pragma unroll
    for (int q = 0; q < 4; ++q) {
      const int s = l4 * 4 + q;
      const float xr = bf2f(xb[s * 192 + jl]);
      const float xz = bf2f(xb[s * 192 + 64 + jl]);
      const float xn = bf2f(xb[s * 192 + 128 + jl]);
      const float rr = sigmoidf_(xr + a0[q] + br);
      const float zz = sigmoidf_(xz + a1[q] + bz);
      const float nn = tanhf_(xn + rr * (a2[q] + bn));
      const float hnew = (1.0f - zz) * nn + zz * h[q];
      __builtin_nontemporal_store(
          f2bf(hnew), &hs[((size_t)(n0 + s) * TT + t) * HH + jfull]);
      const float hp = (domask && mkv[q]) ? 0.0f : hnew;
      h[q] = hp;
      smem[HST_U + s * 72 + jl] = f2bf(hp);
    }
    __syncthreads();   // B3: hStage ready; hAf reads done

    if (domask) {
      // ---- publish: 256 x 8B sc1 relaxed stores in fragment order
      char* dst = ((t + 1) & 1) ? slot1 : slot0;
      const ull_t v = *(const ull_t*)(smem + pSrc);
      __hip_atomic_store((ull_t*)(dst + pOff), v,
                         __ATOMIC_RELAXED, __HIP_MEMORY_SCOPE_AGENT);
      __syncthreads();  // B4: vmcnt(0) -> publishes acked at L3
      if (tid == 0)
        __hip_atomic_store(&flags[bid * 32], (uint_t)(t + 2), __ATOMIC_RELAXED,
                           __HIP_MEMORY_SCOPE_AGENT);
    }
  }

  // ---- epilogue: final h (unmasked) -> hT f32
#pragma unroll
  for (int q = 0; q < 4; ++q)
    hT[(size_t)(n0 + l4 * 4 + q) * HH + jfull] = h[q];
}

// ---------------------------------------------------------------------------
// hx_out[n,t,:] = hT[n,:]  (f32, overwrites the hs scratch region after gemm3)
__global__ void bcast_hT(const float* __restrict__ hT, float* __restrict__ dst) {
  const float4* s = (const float4*)hT;
  float4* d = (float4*)dst;
  const int total = NB * TT * HH / 4;
  const int stride = gridDim.x * blockDim.x;
  for (int c = blockIdx.x * blockDim.x + threadIdx.x; c < total; c += stride) {
    int n = c >> 15;
    int j4 = c & 127;
    d[c] = s[(n << 7) | j4];
  }
}

// ---------------------------------------------------------------------------
extern "C" void kernel_launch(void* const* d_in, const int* in_sizes, int n_in,
                              void* d_out, int out_size, void* d_ws, size_t ws_size,
                              hipStream_t stream) {
  const float* x    = (const float*)d_in[0];
  const float* hx   = (const float*)d_in[1];
  const float* Wih  = (const float*)d_in[2];
  const float* Whh  = (const float*)d_in[3];
  const float* bih  = (const float*)d_in[4];
  const float* bhh  = (const float*)d_in[5];
  const float* Wout = (const float*)d_in[6];
  const float* bout = (const float*)d_in[7];
  const unsigned char* isinit = (const unsigned char*)d_in[8];

  char* ws = (char*)d_ws;
  ushort_t* xi    = (ushort_t*)(ws);
  ushort_t* wihb  = (ushort_t*)(ws + 201326592);
  ushort_t* whhp  = (ushort_t*)(ws + 202899456);
  ushort_t* woutb = (ushort_t*)(ws + 204472320);
  unsigned char* mask8 = (unsigned char*)(ws + 204996608);
  float*    hTbuf = (float*)(ws + 205062144);
  uint_t*   flags = (uint_t*)(ws + 205586432);
  char*     xch   = (char*)(ws + 205602816);

  float* out1 = (float*)d_out;                       // output [N,T,H] f32
  float* out2 = out1 + (size_t)NB * TT * HH;         // hx_out [N,T,H] f32
  ushort_t* hsb = (ushort_t*)out2;  // hs bf16 scratch until bcast overwrites

  hipMemsetAsync(flags, 0, 128 * 32 * sizeof(uint_t), stream);
  mask_detect_kernel<<<1, 1024, 0, stream>>>(isinit, mask8);
  cvt_f2bf<<<768, 256, 0, stream>>>(Wih, wihb, GG * II / 4);
  cvt_f2bf<<<256, 256, 0, stream>>>(Wout, woutb, HH * HH / 4);
  pack_whh<<<384, 256, 0, stream>>>(Whh, whhp);

  dim3 g1(512, 12);  // M/128 x 3H/128
  gemm_bt<1, 0><<<g1, 256, 0, stream>>>((const void*)x, wihb, bih, (void*)xi, GG);

  gru_rec<<<128, 256, 162048, stream>>>(xi, whhp, hx, bhh, mask8, hsb, hTbuf,
                                        xch, flags);

  dim3 g3(512, 4);   // M/128 x H/128
  gemm_bt<0, 1><<<g3, 256, 0, stream>>>((const void*)hsb, woutb, bout, (void*)out1, HH);

  bcast_hT<<<2048, 256, 0, stream>>>(hTbuf, out2);
}

// Round 14
// 1349.286 us; speedup vs baseline: 2.1724x; 1.2372x over previous
//
#include <hip/hip_runtime.h>

// Problem constants
#define NB 256   // batch
#define TT 256   // time steps
#define II 512   // input dim
#define HH 512   // hidden dim
#define GG 1536  // 3*H gates

typedef unsigned short ushort_t;
typedef unsigned int uint_t;
typedef unsigned long long ull_t;
typedef __attribute__((ext_vector_type(8))) short short8;   // 8 x bf16 (4 VGPRs)
typedef __attribute__((ext_vector_type(4))) float f32x4;    // MFMA accumulator

typedef __attribute__((address_space(3))) void lds_void;
typedef const __attribute__((address_space(1))) void glb_void;

__device__ __forceinline__ ushort_t f2bf(float f) {
  union { float f; unsigned int u; } x; x.f = f;
  unsigned int r = x.u + 0x7FFFu + ((x.u >> 16) & 1u);  // RNE
  return (ushort_t)(r >> 16);
}
__device__ __forceinline__ float bf2f(ushort_t b) {
  union { unsigned int u; float f; } x; x.u = ((unsigned int)b) << 16;
  return x.f;
}
__device__ __forceinline__ float sigmoidf_(float x) {
  return __fdividef(1.0f, 1.0f + __expf(-x));
}
__device__ __forceinline__ float tanhf_(float x) {
  float t = __expf(2.0f * x);
  return 1.0f - __fdividef(2.0f, t + 1.0f);
}
__device__ __forceinline__ short8 pack8(float4 a, float4 b) {
  short8 r;
  r[0] = (short)f2bf(a.x); r[1] = (short)f2bf(a.y);
  r[2] = (short)f2bf(a.z); r[3] = (short)f2bf(a.w);
  r[4] = (short)f2bf(b.x); r[5] = (short)f2bf(b.y);
  r[6] = (short)f2bf(b.z); r[7] = (short)f2bf(b.w);
  return r;
}

// ---------------------------------------------------------------------------
// is_init canonicalization -> uint8 mask (handles u8/i32/f32/i64 storage).
__global__ void mask_detect_kernel(const unsigned char* __restrict__ src,
                                   unsigned char* __restrict__ mask8) {
  __shared__ int fByte, fOdd;
  const int tid = threadIdx.x;
  if (tid == 0) { fByte = 0; fOdd = 0; }
  __syncthreads();
  const uint_t* w = (const uint_t*)src;
  int ab = 0, ao = 0;
  for (int i = tid; i < NB * TT; i += blockDim.x) {
    if ((i & 3) == 1 && src[i]) ab = 1;
    if (i < 16384 && (i & 1) == 1 && w[i]) ao = 1;
  }
  if (ab) fByte = 1;
  if (ao) fOdd = 1;
  __syncthreads();
  const int isByte = fByte, isW32 = fOdd;
  for (int i = tid; i < NB * TT; i += blockDim.x) {
    unsigned char m;
    if (isByte)      m = src[i] ? 1 : 0;
    else if (isW32)  m = w[i] ? 1 : 0;
    else             m = w[2 * i] ? 1 : 0;
    mask8[i] = m;
  }
}

// ---------------------------------------------------------------------------
__global__ void cvt_f2bf(const float* __restrict__ src, ushort_t* __restrict__ dst,
                         int n4) {
  int stride = gridDim.x * blockDim.x;
  for (int i = blockIdx.x * blockDim.x + threadIdx.x; i < n4; i += stride) {
    const float4 v = reinterpret_cast<const float4*>(src)[i];
    ushort4 o;
    o.x = f2bf(v.x); o.y = f2bf(v.y); o.z = f2bf(v.z); o.w = f2bf(v.w);
    reinterpret_cast<ushort4*>(dst)[i] = o;
  }
}

// ---------------------------------------------------------------------------
// Pack W_hh [1536][512] f32 into MFMA-B-fragment order (bf16):
// Wpk[((tile*16+kk)*64 + lane)*8 + e] = W[tile*16 + (lane&15)][kk*32 + (lane>>4)*8 + e]
__global__ void pack_whh(const float* __restrict__ W, ushort_t* __restrict__ out) {
  int idx = blockIdx.x * blockDim.x + threadIdx.x;  // 96*16*64 = 98304
  if (idx >= 96 * 16 * 64) return;
  int l = idx & 63;
  int tk = idx >> 6;
  int tile = tk >> 4, kk = tk & 15;
  int row = tile * 16 + (l & 15);
  int k = kk * 32 + (l >> 4) * 8;
  const float* s = W + (size_t)row * HH + k;
  short8 v;
#pragma unroll
  for (int e = 0; e < 8; ++e) v[e] = (short)f2bf(s[e]);
  *reinterpret_cast<short8*>(out + (size_t)idx * 8) = v;
}

// ---------------------------------------------------------------------------
// GEMM: C[m][c] = sum_k A[m][k]*B[c][k] + bias[c].  (unchanged)
template <int AF32, int CF32>
__global__ __launch_bounds__(256) void gemm_bt(
    const void* __restrict__ Av, const ushort_t* __restrict__ B,
    const float* __restrict__ bias, void* __restrict__ Cv, int NC) {
  __shared__ ushort_t As[128 * 32];
  __shared__ ushort_t Bs[128 * 32];
  const int tid = threadIdx.x;
  const int lane = tid & 63;
  const int w = tid >> 6;
  const int wr = w >> 1, wc = w & 1;
  const int c15 = lane & 15, l4 = lane >> 4;
  const int mbase = blockIdx.x * 128;
  const int nbase = blockIdx.y * 128;

  const int rs = tid >> 2;
  const int kb = (tid & 3) * 8;

  f32x4 acc[4][4] = {};

  const float4* Bg = reinterpret_cast<const float4*>(B);
  auto bIdx = [&](int c, int kt) {
    return ((size_t)(nbase + rs + 64 * c) * 512 + kt * 32 + kb) >> 3;
  };
  float4 rb0 = Bg[bIdx(0, 0)], rb1 = Bg[bIdx(1, 0)];

  const float4* Agf = reinterpret_cast<const float4*>(Av);
  auto aEl = [&](int c, int kt) {
    return (size_t)(mbase + rs + 64 * c) * 512 + kt * 32 + kb;
  };
  float4 a0a, a0b, a1a, a1b;
  float4 h0, h1;
  if constexpr (AF32) {
    a0a = Agf[aEl(0, 0) >> 2]; a0b = Agf[(aEl(0, 0) >> 2) + 1];
    a1a = Agf[aEl(1, 0) >> 2]; a1b = Agf[(aEl(1, 0) >> 2) + 1];
  } else {
    h0 = Agf[aEl(0, 0) >> 3];
    h1 = Agf[aEl(1, 0) >> 3];
  }

  for (int kt = 0; kt < 16; ++kt) {
    __syncthreads();
    if constexpr (AF32) {
      *reinterpret_cast<short8*>(&As[(size_t)tid * 8]) = pack8(a0a, a0b);
      *reinterpret_cast<short8*>(&As[(size_t)(tid + 256) * 8]) = pack8(a1a, a1b);
    } else {
      reinterpret_cast<float4*>(As)[tid] = h0;
      reinterpret_cast<float4*>(As)[tid + 256] = h1;
    }
    reinterpret_cast<float4*>(Bs)[tid] = rb0;
    reinterpret_cast<float4*>(Bs)[tid + 256] = rb1;
    if (kt < 15) {
      if constexpr (AF32) {
        a0a = Agf[aEl(0, kt + 1) >> 2]; a0b = Agf[(aEl(0, kt + 1) >> 2) + 1];
        a1a = Agf[aEl(1, kt + 1) >> 2]; a1b = Agf[(aEl(1, kt + 1) >> 2) + 1];
      } else {
        h0 = Agf[aEl(0, kt + 1) >> 3];
        h1 = Agf[aEl(1, kt + 1) >> 3];
      }
      rb0 = Bg[bIdx(0, kt + 1)]; rb1 = Bg[bIdx(1, kt + 1)];
    }
    __syncthreads();
    short8 af[4], bq[4];
#pragma unroll
    for (int m = 0; m < 4; ++m)
      af[m] = *reinterpret_cast<const short8*>(&As[(wr * 64 + m * 16 + c15) * 32 + l4 * 8]);
#pragma unroll
    for (int n = 0; n < 4; ++n)
      bq[n] = *reinterpret_cast<const short8*>(&Bs[(wc * 64 + n * 16 + c15) * 32 + l4 * 8]);
#pragma unroll
    for (int m = 0; m < 4; ++m)
#pragma unroll
      for (int n = 0; n < 4; ++n)
        acc[m][n] = __builtin_amdgcn_mfma_f32_16x16x32_bf16(af[m], bq[n], acc[m][n], 0, 0, 0);
  }

#pragma unroll
  for (int n = 0; n < 4; ++n) {
    const int col = nbase + wc * 64 + n * 16 + c15;
    const float bv = bias[col];
#pragma unroll
    for (int m = 0; m < 4; ++m) {
      const int row = mbase + wr * 64 + m * 16 + l4 * 4;
#pragma unroll
      for (int q = 0; q < 4; ++q) {
        const float v = acc[m][n][q] + bv;
        if constexpr (CF32)
          reinterpret_cast<float*>(Cv)[(size_t)(row + q) * NC + col] = v;
        else
          reinterpret_cast<ushort_t*>(Cv)[(size_t)(row + q) * NC + col] = f2bf(v);
      }
    }
  }
}

// ---------------------------------------------------------------------------
// GRU recurrence v12: TAGGED-WORD exchange (no flags, no fences, no XCD
// assumptions). Each published h value is a 4B word = bf16<<16 | step_tag.
// Consumers poll the data words directly via sc1 (agent-scope relaxed)
// loads; retry until every word of the cluster's h(t) carries tag t+1.
// Why this is safe with 2 slots and NO flag barrier: a block can publish
// h(t+2) into slot[t&1] only after its gather of h(t+1) succeeded, which
// requires every peer to have published h(t+1), which (per-thread data
// dependency) requires every peer to have finished reading h(t). The tag
// gather IS the barrier. Per-launch memset of xch kills cross-replay ABA.
// Single-writer-per-word + 4B store atomicity + L3 coherence point (sc1,
// verified passing in v8/v9) => placement-independent correctness [G16].
// LDS map (ushort idx): Wlds 0..65535 | hAf 65536..73727 | xiL 73728..79871
//                       | hStage 79872..81023   (dynamic total 162048 B)
__global__ __launch_bounds__(256, 1) void gru_rec(
    const ushort_t* __restrict__ xi, const ushort_t* __restrict__ Wpk,
    const float* __restrict__ hx, const float* __restrict__ bhh,
    const unsigned char* __restrict__ mask8,
    ushort_t* __restrict__ hs, float* __restrict__ hT,
    char* __restrict__ xch) {
  extern __shared__ ushort_t smem[];
  const int HAF_U = 65536, XIL_U = 73728, HST_U = 79872;

  const int tid = threadIdx.x;
  const int lane = tid & 63;
  const int w = tid >> 6;              // wave 0..3 -> col-tile
  const int c15 = lane & 15, l4 = lane >> 4;
  const int bid = blockIdx.x;
  const int a = bid & 7;               // hidden-col group
  const int b = bid >> 3;              // sample group (cluster)
  const int n0 = b * 16;

  const int jl = w * 16 + c15;         // [0,64) local hidden col
  const int jfull = a * 64 + jl;       // [0,512)
  const float br = bhh[jfull], bz = bhh[512 + jfull], bn = bhh[1024 + jfull];

  // ---- prologue DMA: W gates r,z -> LDS (32 x 1KB per wave)
#pragma unroll
  for (int g = 0; g < 2; ++g)
#pragma unroll
    for (int kk = 0; kk < 16; ++kk)
      __builtin_amdgcn_global_load_lds(
          (glb_void*)(Wpk + ((size_t)((g * 32 + a * 4 + w) * 16 + kk)) * 512 + lane * 8),
          (lds_void*)(smem + w * 16384 + (g * 16 + kk) * 512 + lane * 8), 16, 0, 0);

  // ---- gate-n W slice into registers (loaded once)
  const int wb2 = ((2 * 32 + a * 4 + w) * 16) * 512 + lane * 8;
  short8 wn[16];
#pragma unroll
  for (int kk = 0; kk < 16; ++kk)
    wn[kk] = *(const short8*)(Wpk + wb2 + kk * 512);

  // xi DMA geometry: 384 chunks = [16 s][3 g][8 p]; thread: c=tid, c=tid+256
  size_t xg0, xg1 = 0;
  {
    int c = tid, s = c / 24, r = c % 24, g = r >> 3, p = r & 7;
    xg0 = ((size_t)(n0 + s) * TT) * GG + g * 512 + a * 64 + p * 8;
    if (tid < 128) {
      c = tid + 256; s = c / 24; r = c % 24; g = r >> 3; p = r & 7;
      xg1 = ((size_t)(n0 + s) * TT) * GG + g * 512 + a * 64 + p * 8;
    }
  }
  const int xl0 = tid * 8, xl1 = (tid + 256) * 8;

  // tagged exchange slots (32KB each): word w = bf16<<16 | tag;
  // word index w == LDS hAf bf16 index w (fragment order, v9 mapping)
  char* slot0 = xch + (size_t)(b * 2) * 32768;
  char* slot1 = xch + (size_t)(b * 2 + 1) * 32768;

  // publish geometry: 4 bf16 (old 8B chunk pOff) -> 4 words at byte pOff*2
  const int ps = tid >> 4, pj = tid & 15;
  const int pOff = (2 * a + (pj >> 3)) * 1024 +
                   (ps + 16 * ((pj >> 1) & 3)) * 16 + (pj & 1) * 8;
  const int pSrc = HST_U + ps * 72 + pj * 4;   // ushort idx into hStage

  auto publish = [&](char* slot, uint_t tag) {
    const uint_t h0 = smem[pSrc], h1 = smem[pSrc + 1];
    const uint_t h2 = smem[pSrc + 2], h3 = smem[pSrc + 3];
    const ull_t w0 = ((ull_t)(h0 << 16 | tag)) | (((ull_t)(h1 << 16 | tag)) << 32);
    const ull_t w1 = ((ull_t)(h2 << 16 | tag)) | (((ull_t)(h3 << 16 | tag)) << 32);
    char* d = slot + (size_t)pOff * 2;
    __hip_atomic_store((ull_t*)d, w0, __ATOMIC_RELAXED, __HIP_MEMORY_SCOPE_AGENT);
    __hip_atomic_store((ull_t*)(d + 8), w1, __ATOMIC_RELAXED, __HIP_MEMORY_SCOPE_AGENT);
  };

  // ---- stage + publish h(0) (tag 1)
  float h[4];
#pragma unroll
  for (int q = 0; q < 4; ++q) {
    const int s = l4 * 4 + q;
    const bool mk0 = mask8[(size_t)(n0 + s) * TT] != 0;
    const float v = mk0 ? 0.0f : hx[((size_t)(n0 + s) * TT) * HH + jfull];
    h[q] = v;
    smem[HST_U + s * 72 + jl] = f2bf(v);
  }
  __syncthreads();
  publish(slot0, 1u);

  for (int t = 0; t < TT; ++t) {
    // ---- issue xi(t) DMA into buffer t&1 (overlaps the poll)
    ushort_t* xb = smem + XIL_U + (t & 1) * 3072;
    __builtin_amdgcn_global_load_lds((glb_void*)(xi + xg0 + (size_t)t * GG),
                                     (lds_void*)(xb + xl0), 16, 0, 0);
    if (tid < 128)
      __builtin_amdgcn_global_load_lds((glb_void*)(xi + xg1 + (size_t)t * GG),
                                       (lds_void*)(xb + xl1), 16, 0, 0);

    // ---- gather h(t): poll tagged words (tag == t+1), sc1 batched loads
    const char* src = (t & 1) ? slot1 : slot0;
    const uint_t tgt = (uint_t)(t + 1);
    ull_t v[16];
    bool ok;
    do {
      ok = true;
#pragma unroll
      for (int i = 0; i < 16; ++i)
        v[i] = __hip_atomic_load((const ull_t*)(src + ((size_t)(tid + i * 256)) * 8),
                                 __ATOMIC_RELAXED, __HIP_MEMORY_SCOPE_AGENT);
#pragma unroll
      for (int i = 0; i < 16; ++i)
        ok &= (((uint_t)v[i] & 0xFFFFu) == tgt) &&
              (((uint_t)(v[i] >> 32) & 0xFFFFu) == tgt);
    } while (!ok);
    // extract bf16 pairs -> hAf (LDS 4B at chunk*4; linear, conflict-light)
#pragma unroll
    for (int i = 0; i < 16; ++i) {
      const uint_t lo = (uint_t)(v[i] >> 16) & 0xFFFFu;
      const uint_t hi = (uint_t)(v[i] >> 48);
      *(uint_t*)((char*)smem + HAF_U * 2 + ((size_t)(tid + i * 256)) * 4) =
          lo | (hi << 16);
    }

    // next-step mask bytes
    const bool domask = (t + 1 < TT);
    const int tn = domask ? (t + 1) : t;
    unsigned char mkv[4];
#pragma unroll
    for (int q = 0; q < 4; ++q)
      mkv[q] = mask8[(size_t)(n0 + l4 * 4 + q) * TT + tn];

    __syncthreads();   // B2: hAf ready; xi + W DMA drained

    // ---- MFMA: af linear b128; W r,z from LDS; W n from regs
    short8 af[16];
#pragma unroll
    for (int kk = 0; kk < 16; ++kk)
      af[kk] = *(const short8*)((char*)smem + HAF_U * 2 + kk * 1024 + lane * 16);

    f32x4 a0 = {0.f, 0.f, 0.f, 0.f}, a1 = a0, a2 = a0;
#pragma unroll
    for (int kk = 0; kk < 16; ++kk) {
      const short8 w0 = *(const short8*)(smem + w * 16384 + kk * 512 + lane * 8);
      const short8 w1 = *(const short8*)(smem + w * 16384 + (16 + kk) * 512 + lane * 8);
      a0 = __builtin_amdgcn_mfma_f32_16x16x32_bf16(af[kk], w0, a0, 0, 0, 0);
      a1 = __builtin_amdgcn_mfma_f32_16x16x32_bf16(af[kk], w1, a1, 0, 0, 0);
      a2 = __builtin_amdgcn_mfma_f32_16x16x32_bf16(af[kk], wn[kk], a2, 0, 0, 0);
    }

    // ---- gates + h update; hs nontemporal; stage h(t+1) in LDS
#pragma unroll
    for (int q = 0; q < 4; ++q) {
      const int s = l4 * 4 + q;
      const float xr = bf2f(xb[s * 192 + jl]);
      const float xz = bf2f(xb[s * 192 + 64 + jl]);
      const float xn = bf2f(xb[s * 192 + 128 + jl]);
      const float rr = sigmoidf_(xr + a0[q] + br);
      const float zz = sigmoidf_(xz + a1[q] + bz);
      const float nn = tanhf_(xn + rr * (a2[q] + bn));
      const float hnew = (1.0f - zz) * nn + zz * h[q];
      __builtin_nontemporal_store(
          f2bf(hnew), &hs[((size_t)(n0 + s) * TT + t) * HH + jfull]);
      const float hp = (domask && mkv[q]) ? 0.0f : hnew;
      h[q] = hp;
      smem[HST_U + s * 72 + jl] = f2bf(hp);
    }
    __syncthreads();   // B3: hStage complete; hAf reads done

    // ---- publish h(t+1) tagged t+2 (fire-and-forget; no flag, no drain)
    if (domask)
      publish(((t + 1) & 1) ? slot1 : slot0, (uint_t)(t + 2));
  }

  // ---- epilogue: final h (unmasked) -> hT f32
#pragma unroll
  for (int q = 0; q < 4; ++q)
    hT[(size_t)(n0 + l4 * 4 + q) * HH + jfull] = h[q];
}

// ---------------------------------------------------------------------------
// hx_out[n,t,:] = hT[n,:]  (f32, overwrites the hs scratch region after gemm3)
__global__ void bcast_hT(const float* __restrict__ hT, float* __restrict__ dst) {
  const float4* s = (const float4*)hT;
  float4* d = (float4*)dst;
  const int total = NB * TT * HH / 4;
  const int stride = gridDim.x * blockDim.x;
  for (int c = blockIdx.x * blockDim.x + threadIdx.x; c < total; c += stride) {
    int n = c >> 15;
    int j4 = c & 127;
    d[c] = s[(n << 7) | j4];
  }
}

// ---------------------------------------------------------------------------
extern "C" void kernel_launch(void* const* d_in, const int* in_sizes, int n_in,
                              void* d_out, int out_size, void* d_ws, size_t ws_size,
                              hipStream_t stream) {
  const float* x    = (const float*)d_in[0];
  const float* hx   = (const float*)d_in[1];
  const float* Wih  = (const float*)d_in[2];
  const float* Whh  = (const float*)d_in[3];
  const float* bih  = (const float*)d_in[4];
  const float* bhh  = (const float*)d_in[5];
  const float* Wout = (const float*)d_in[6];
  const float* bout = (const float*)d_in[7];
  const unsigned char* isinit = (const unsigned char*)d_in[8];

  char* ws = (char*)d_ws;
  ushort_t* xi    = (ushort_t*)(ws);
  ushort_t* wihb  = (ushort_t*)(ws + 201326592);
  ushort_t* whhp  = (ushort_t*)(ws + 202899456);
  ushort_t* woutb = (ushort_t*)(ws + 204472320);
  unsigned char* mask8 = (unsigned char*)(ws + 204996608);
  float*    hTbuf = (float*)(ws + 205062144);
  char*     xch   = (char*)(ws + 205602816);  // 16 clusters x 2 slots x 32KB = 1MB

  float* out1 = (float*)d_out;                       // output [N,T,H] f32
  float* out2 = out1 + (size_t)NB * TT * HH;         // hx_out [N,T,H] f32
  ushort_t* hsb = (ushort_t*)out2;  // hs bf16 scratch until bcast overwrites

  hipMemsetAsync(xch, 0, 1 << 20, stream);  // zero tags (cross-replay ABA)
  mask_detect_kernel<<<1, 1024, 0, stream>>>(isinit, mask8);
  cvt_f2bf<<<768, 256, 0, stream>>>(Wih, wihb, GG * II / 4);
  cvt_f2bf<<<256, 256, 0, stream>>>(Wout, woutb, HH * HH / 4);
  pack_whh<<<384, 256, 0, stream>>>(Whh, whhp);

  dim3 g1(512, 12);  // M/128 x 3H/128
  gemm_bt<1, 0><<<g1, 256, 0, stream>>>((const void*)x, wihb, bih, (void*)xi, GG);

  gru_rec<<<128, 256, 162048, stream>>>(xi, whhp, hx, bhh, mask8, hsb, hTbuf,
                                        xch);

  dim3 g3(512, 4);   // M/128 x H/128
  gemm_bt<0, 1><<<g3, 256, 0, stream>>>((const void*)hsb, woutb, bout, (void*)out1, HH);

  bcast_hT<<<2048, 256, 0, stream>>>(hTbuf, out2);
}